// Round 1
// baseline (475.785 us; speedup 1.0000x reference)
//
#include <hip/hip_runtime.h>

#define NN 100000
#define NE 600000
#define DD 128

// ---------------------------------------------------------------------------
// edge_index dtype detection: reference declares int64, but JAX default
// (x64 disabled) yields int32. For int64 (values < 2^31), every odd 32-bit
// word is 0; for random int32 indices in [0,100000) that is impossible over
// 128 samples. Writes 1 (int64) or 0 (int32) to *flag.
// ---------------------------------------------------------------------------
__global__ void detect_idx64_kernel(const unsigned int* __restrict__ raw,
                                    int* __restrict__ flag) {
  if (threadIdx.x == 0 && blockIdx.x == 0) {
    int is64 = 1;
#pragma unroll 1
    for (int i = 0; i < 128; ++i) {
      if (raw[2 * i + 1] != 0u) { is64 = 0; break; }
    }
    *flag = is64;
  }
}

// ---------------------------------------------------------------------------
// 64-row x 128-col x K=128 GEMM micro-kernel.
// 256 threads: tx = tid&31 -> 4 contiguous cols (j0 = 4*tx),
//              ty = tid>>5 -> 8 rows (ty*8 .. ty*8+7).
// S_lds: [64][128] row-major fp32 in LDS (reads along k are wave broadcasts).
// Wg:    [128][128] row-major fp32 in global (L2-resident, coalesced float4).
// acc[r][c] += sum_k S[ty*8+r][k] * Wg[k][j0+c]
// ---------------------------------------------------------------------------
__device__ __forceinline__ void gemm_8x4_acc(const float* __restrict__ S_lds,
                                             const float* __restrict__ Wg,
                                             int ty, int tx,
                                             float acc[8][4]) {
  const int j0 = tx * 4;
#pragma unroll 2
  for (int k0 = 0; k0 < DD; k0 += 4) {
    float xa[8][4];
#pragma unroll
    for (int r = 0; r < 8; ++r) {
      const float4 v =
          *reinterpret_cast<const float4*>(S_lds + (ty * 8 + r) * DD + k0);
      xa[r][0] = v.x; xa[r][1] = v.y; xa[r][2] = v.z; xa[r][3] = v.w;
    }
    float wa[4][4];
#pragma unroll
    for (int kk = 0; kk < 4; ++kk) {
      const float4 w =
          *reinterpret_cast<const float4*>(Wg + (size_t)(k0 + kk) * DD + j0);
      wa[kk][0] = w.x; wa[kk][1] = w.y; wa[kk][2] = w.z; wa[kk][3] = w.w;
    }
#pragma unroll
    for (int kk = 0; kk < 4; ++kk)
#pragma unroll
      for (int r = 0; r < 8; ++r)
#pragma unroll
        for (int c = 0; c < 4; ++c)
          acc[r][c] = fmaf(xa[r][kk], wa[kk][c], acc[r][c]);
  }
}

// ---------------------------------------------------------------------------
// Phase 1: per-node tables.
//   A[n] = (sigmoid(x W_src) * x) @ W_proj[:128]  + b_proj
//   B[n] = (sigmoid(x W_tgt) * x) @ W_proj[128:]
// 64 nodes per block.
// ---------------------------------------------------------------------------
__launch_bounds__(256, 2)
__global__ void phase1_kernel(const float* __restrict__ Xg,
                              const float* __restrict__ Wsrc,
                              const float* __restrict__ Wtgt,
                              const float* __restrict__ Wproj,
                              const float* __restrict__ bproj,
                              float* __restrict__ Aout,
                              float* __restrict__ Bout) {
  __shared__ float Xs[64 * DD];
  __shared__ float Ts[64 * DD];
  const int tid = (int)threadIdx.x;
  const int row0 = (int)blockIdx.x * 64;
  const int rem = NN - row0;
  const int nvalid = rem < 64 ? rem : 64;

  // stage X tile (zero-fill invalid rows)
  for (int i = tid; i < 64 * (DD / 4); i += 256) {
    const int m = i >> 5;
    const int c4 = i & 31;
    float4 v = make_float4(0.f, 0.f, 0.f, 0.f);
    if (m < nvalid)
      v = reinterpret_cast<const float4*>(Xg + (size_t)(row0 + m) * DD)[c4];
    reinterpret_cast<float4*>(Xs + m * DD)[c4] = v;
  }
  __syncthreads();

  const int tx = tid & 31;
  const int ty = tid >> 5;
  const int j0 = tx * 4;
  const float4 bp = reinterpret_cast<const float4*>(bproj)[tx];

#pragma unroll 1
  for (int pass = 0; pass < 2; ++pass) {
    const float* __restrict__ Wg = pass ? Wtgt : Wsrc;

    // S = X @ Wg  (gate pre-activation)
    float acc[8][4];
#pragma unroll
    for (int r = 0; r < 8; ++r)
#pragma unroll
      for (int c = 0; c < 4; ++c) acc[r][c] = 0.f;
    gemm_8x4_acc(Xs, Wg, ty, tx, acc);

    // T = sigmoid(S) * X   (sync: pass 1 must wait for pass 0's GEMM2 reads)
    __syncthreads();
#pragma unroll
    for (int r = 0; r < 8; ++r) {
      const float4 xr =
          *reinterpret_cast<const float4*>(Xs + (ty * 8 + r) * DD + j0);
      float4 t;
      t.x = xr.x / (1.f + __expf(-acc[r][0]));
      t.y = xr.y / (1.f + __expf(-acc[r][1]));
      t.z = xr.z / (1.f + __expf(-acc[r][2]));
      t.w = xr.w / (1.f + __expf(-acc[r][3]));
      *reinterpret_cast<float4*>(Ts + (ty * 8 + r) * DD + j0) = t;
    }
    __syncthreads();

    // table = T @ Wproj_half (+ b_proj for the A half)
    float acc2[8][4];
#pragma unroll
    for (int r = 0; r < 8; ++r)
#pragma unroll
      for (int c = 0; c < 4; ++c) acc2[r][c] = 0.f;
    const float* __restrict__ Wp = Wproj + (size_t)(pass ? DD * DD : 0);
    gemm_8x4_acc(Ts, Wp, ty, tx, acc2);

    float* __restrict__ dst = pass ? Bout : Aout;
    const float bx = pass ? 0.f : bp.x;
    const float by = pass ? 0.f : bp.y;
    const float bz = pass ? 0.f : bp.z;
    const float bw = pass ? 0.f : bp.w;
#pragma unroll
    for (int r = 0; r < 8; ++r) {
      const int m = ty * 8 + r;
      if (m < nvalid) {
        float4 o;
        o.x = acc2[r][0] + bx;
        o.y = acc2[r][1] + by;
        o.z = acc2[r][2] + bz;
        o.w = acc2[r][3] + bw;
        *reinterpret_cast<float4*>(dst + (size_t)(row0 + m) * DD + j0) = o;
      }
    }
  }
}

// ---------------------------------------------------------------------------
// Phase 2: per-edge   out[e] = relu(A[src_e] + B[tgt_e]) @ W_mlp + b_mlp
// 64 edges per block (600000 = 9375 * 64, no tail).
// ---------------------------------------------------------------------------
__launch_bounds__(256, 2)
__global__ void phase2_kernel(const float* __restrict__ At,
                              const float* __restrict__ Bt,
                              const unsigned int* __restrict__ eraw,
                              const int* __restrict__ flag_p,
                              const float* __restrict__ Wmlp,
                              const float* __restrict__ bmlp,
                              float* __restrict__ out) {
  __shared__ float Rs[64 * DD];
  __shared__ int sidx[64];
  __shared__ int tidx[64];
  const int tid = (int)threadIdx.x;
  const int e0 = (int)blockIdx.x * 64;
  const int is64 = *flag_p;

  if (tid < 64) {
    const size_t e = (size_t)(e0 + tid);
    if (is64) {
      sidx[tid] = (int)eraw[2 * e];
      tidx[tid] = (int)eraw[2 * ((size_t)NE + e)];
    } else {
      sidx[tid] = (int)eraw[e];
      tidx[tid] = (int)eraw[(size_t)NE + e];
    }
  }
  __syncthreads();

  // gather + relu into Rs
  {
    const int c4 = tid & 31;
    const int tg = tid >> 5;
#pragma unroll
    for (int i = 0; i < 8; ++i) {
      const int m = i * 8 + tg;
      const float4 av =
          reinterpret_cast<const float4*>(At + (size_t)sidx[m] * DD)[c4];
      const float4 bv =
          reinterpret_cast<const float4*>(Bt + (size_t)tidx[m] * DD)[c4];
      float4 r;
      r.x = fmaxf(av.x + bv.x, 0.f);
      r.y = fmaxf(av.y + bv.y, 0.f);
      r.z = fmaxf(av.z + bv.z, 0.f);
      r.w = fmaxf(av.w + bv.w, 0.f);
      reinterpret_cast<float4*>(Rs + m * DD)[c4] = r;
    }
  }
  __syncthreads();

  const int tx = tid & 31;
  const int ty = tid >> 5;
  const int j0 = tx * 4;

  float acc[8][4];
#pragma unroll
  for (int r = 0; r < 8; ++r)
#pragma unroll
    for (int c = 0; c < 4; ++c) acc[r][c] = 0.f;
  gemm_8x4_acc(Rs, Wmlp, ty, tx, acc);

  const float4 bm = reinterpret_cast<const float4*>(bmlp)[tx];
#pragma unroll
  for (int r = 0; r < 8; ++r) {
    const int m = ty * 8 + r;
    float4 o;
    o.x = acc[r][0] + bm.x;
    o.y = acc[r][1] + bm.y;
    o.z = acc[r][2] + bm.z;
    o.w = acc[r][3] + bm.w;
    *reinterpret_cast<float4*>(out + (size_t)(e0 + m) * DD + j0) = o;
  }
}

// ---------------------------------------------------------------------------
extern "C" void kernel_launch(void* const* d_in, const int* in_sizes, int n_in,
                              void* d_out, int out_size, void* d_ws,
                              size_t ws_size, hipStream_t stream) {
  (void)in_sizes; (void)n_in; (void)out_size; (void)ws_size;

  const float* X = (const float*)d_in[0];
  const unsigned int* eraw = (const unsigned int*)d_in[1];
  const float* Wsrc = (const float*)d_in[2];
  const float* Wtgt = (const float*)d_in[3];
  const float* Wproj = (const float*)d_in[4];
  const float* bproj = (const float*)d_in[5];
  const float* Wmlp = (const float*)d_in[6];
  const float* bmlp = (const float*)d_in[7];
  float* out = (float*)d_out;

  // workspace layout: A[N*128] f32 | B[N*128] f32 | flag (int)
  float* A = (float*)d_ws;
  float* B = A + (size_t)NN * DD;
  int* flag = (int*)(B + (size_t)NN * DD);

  detect_idx64_kernel<<<1, 64, 0, stream>>>(eraw, flag);
  phase1_kernel<<<(NN + 63) / 64, 256, 0, stream>>>(X, Wsrc, Wtgt, Wproj,
                                                    bproj, A, B);
  phase2_kernel<<<NE / 64, 256, 0, stream>>>(A, B, eraw, flag, Wmlp, bmlp,
                                             out);
}

// Round 2
// 240.646 us; speedup vs baseline: 1.9771x; 1.9771x over previous
//
#include <hip/hip_runtime.h>

#define NN 100000
#define NE 600000
#define DD 128

typedef _Float16 half4_t __attribute__((ext_vector_type(4)));
typedef _Float16 half8_t __attribute__((ext_vector_type(8)));
typedef float f32x4 __attribute__((ext_vector_type(4)));

// XOR-swizzle for [row][256B] f16 LDS tiles: spreads same-column reads of 8
// consecutive rows across 8 distinct 16B slots (G4 fix; rows r and r+8 alias
// = 2-way = free per m136). Returns BYTE address; all uses keep alignment.
__device__ __forceinline__ int swz16(int row, int byte) {
  return row * 256 + (byte ^ ((row & 7) << 4));
}

// ---------------------------------------------------------------------------
// edge_index dtype detection (int64 per reference vs int32 from default JAX).
// ---------------------------------------------------------------------------
__global__ void detect_idx64_kernel(const unsigned int* __restrict__ raw,
                                    int* __restrict__ flag) {
  if (threadIdx.x == 0 && blockIdx.x == 0) {
    int is64 = 1;
#pragma unroll 1
    for (int i = 0; i < 128; ++i) {
      if (raw[2 * i + 1] != 0u) { is64 = 0; break; }
    }
    *flag = is64;
  }
}

// ---------------------------------------------------------------------------
// Pack 5 weight matrices (128x128 f32, row-major [k][n]) into f16 MFMA
// B-fragment order: packed[m][(nf*4+ks)*64 + l][j] = W[8*(l>>4)+32*ks+j][16*nf+(l&15)]
// m: 0=W_src 1=W_tgt 2=W_proj[:128] 3=W_proj[128:] 4=W_mlp
// ---------------------------------------------------------------------------
__global__ void pack_weights_kernel(const float* __restrict__ Wsrc,
                                    const float* __restrict__ Wtgt,
                                    const float* __restrict__ Wproj,
                                    const float* __restrict__ Wmlp,
                                    _Float16* __restrict__ packed) {
  const int t = (int)blockIdx.x * 256 + (int)threadIdx.x;
  if (t >= 5 * 2048) return;
  const int m = t >> 11;
  const int rem = t & 2047;
  const int nf = rem >> 8;
  const int ks = (rem >> 6) & 3;
  const int l = rem & 63;
  const float* W;
  if (m == 0) W = Wsrc;
  else if (m == 1) W = Wtgt;
  else if (m == 2) W = Wproj;
  else if (m == 3) W = Wproj + 128 * DD;
  else W = Wmlp;
  const int col = (l & 15) + 16 * nf;
  const int k0 = 8 * (l >> 4) + 32 * ks;
  half8_t v;
#pragma unroll
  for (int j = 0; j < 8; ++j) v[j] = (_Float16)W[(size_t)(k0 + j) * DD + col];
  *reinterpret_cast<half8_t*>(packed + (size_t)m * 16384 + (size_t)rem * 8) = v;
}

// ---------------------------------------------------------------------------
// Phase 1: per-node tables (f16 out).
//   A[n] = (sigmoid(x W_src) * x) @ W_proj[:128] + b_proj
//   B[n] = (sigmoid(x W_tgt) * x) @ W_proj[128:]
// 64 nodes/block, 4 waves; wave w owns rows [w*16, w*16+16).
// ---------------------------------------------------------------------------
__global__ __launch_bounds__(256)
void phase1_kernel(const float* __restrict__ Xg,
                   const _Float16* __restrict__ packW,
                   const float* __restrict__ bproj,
                   _Float16* __restrict__ Aout,
                   _Float16* __restrict__ Bout) {
  __shared__ _Float16 Xs[64 * DD];
  __shared__ _Float16 Ts[64 * DD];
  const int tid = (int)threadIdx.x;
  const int row0 = (int)blockIdx.x * 64;
  const int rem = NN - row0;
  const int nvalid = rem < 64 ? rem : 64;

  // stage X tile -> f16 LDS (swizzled). 64 rows x 32 float4-groups.
  for (int i = tid; i < 64 * 32; i += 256) {
    const int r = i >> 5;
    const int c4 = i & 31;  // which group of 4 cols
    float4 v = make_float4(0.f, 0.f, 0.f, 0.f);
    if (r < nvalid)
      v = reinterpret_cast<const float4*>(Xg + (size_t)(row0 + r) * DD)[c4];
    half4_t h;
    h[0] = (_Float16)v.x; h[1] = (_Float16)v.y;
    h[2] = (_Float16)v.z; h[3] = (_Float16)v.w;
    *reinterpret_cast<half4_t*>(&Xs[swz16(r, c4 * 8) >> 1]) = h;
  }
  __syncthreads();

  const int l = tid & 63;
  const int w = tid >> 6;       // wave id: rows w*16..w*16+15
  const int lr = l & 15;        // fragment row/col lane part
  const int lg = l >> 4;        // k-group
  const int wrow = w * 16;

#pragma unroll 1
  for (int p = 0; p < 2; ++p) {
    // ---- GEMM1: S = X @ Wgate ----
    const _Float16* Wg = packW + (size_t)p * 16384;
    f32x4 acc[8];
#pragma unroll
    for (int nf = 0; nf < 8; ++nf) acc[nf] = (f32x4)0.f;
#pragma unroll
    for (int ks = 0; ks < 4; ++ks) {
      const half8_t a = *reinterpret_cast<const half8_t*>(
          &Xs[swz16(wrow + lr, lg * 16 + ks * 64) >> 1]);
#pragma unroll
      for (int nf = 0; nf < 8; ++nf) {
        const half8_t b = *reinterpret_cast<const half8_t*>(
            Wg + ((size_t)(nf * 4 + ks) * 64 + l) * 8);
        acc[nf] = __builtin_amdgcn_mfma_f32_16x16x32_f16(a, b, acc[nf], 0, 0, 0);
      }
    }

    // ---- T = sigmoid(S) * X ----
    __syncthreads();  // pass 1: protect Ts against lagging GEMM2 readers
#pragma unroll
    for (int nf = 0; nf < 8; ++nf) {
      const int col = nf * 16 + lr;
#pragma unroll
      for (int reg = 0; reg < 4; ++reg) {
        const int r = wrow + lg * 4 + reg;
        const float x = (float)Xs[swz16(r, col * 2) >> 1];
        const float s = acc[nf][reg];
        const float t = x / (1.f + __expf(-s));
        Ts[swz16(r, col * 2) >> 1] = (_Float16)t;
      }
    }
    __syncthreads();

    // ---- GEMM2: table = T @ Wproj_half (+ b_proj for A) ----
    const _Float16* Wp = packW + (size_t)(2 + p) * 16384;
    f32x4 acc2[8];
#pragma unroll
    for (int nf = 0; nf < 8; ++nf) acc2[nf] = (f32x4)0.f;
#pragma unroll
    for (int ks = 0; ks < 4; ++ks) {
      const half8_t a = *reinterpret_cast<const half8_t*>(
          &Ts[swz16(wrow + lr, lg * 16 + ks * 64) >> 1]);
#pragma unroll
      for (int nf = 0; nf < 8; ++nf) {
        const half8_t b = *reinterpret_cast<const half8_t*>(
            Wp + ((size_t)(nf * 4 + ks) * 64 + l) * 8);
        acc2[nf] = __builtin_amdgcn_mfma_f32_16x16x32_f16(a, b, acc2[nf], 0, 0, 0);
      }
    }

    _Float16* dst = p ? Bout : Aout;
#pragma unroll
    for (int nf = 0; nf < 8; ++nf) {
      const int col = nf * 16 + lr;
      const float bias = p ? 0.f : bproj[col];
#pragma unroll
      for (int reg = 0; reg < 4; ++reg) {
        const int r = wrow + lg * 4 + reg;
        if (r < nvalid)
          dst[(size_t)(row0 + r) * DD + col] = (_Float16)(acc2[nf][reg] + bias);
      }
    }
    __syncthreads();  // protect Ts before next pass overwrites
  }
}

// ---------------------------------------------------------------------------
// Phase 2: out[e] = relu(A[src_e] + B[tgt_e]) @ W_mlp + b_mlp   (f32 out)
// 128 edges/block, 4 waves; wave w owns rows [w*32, w*32+32) (2 m-frags).
// ---------------------------------------------------------------------------
__global__ __launch_bounds__(256)
void phase2_kernel(const _Float16* __restrict__ At,
                   const _Float16* __restrict__ Bt,
                   const unsigned int* __restrict__ eraw,
                   const int* __restrict__ flag_p,
                   const _Float16* __restrict__ Wmlp_pk,  // packed idx 4
                   const float* __restrict__ bmlp,
                   float* __restrict__ out) {
  __shared__ _Float16 Rs[128 * DD];
  __shared__ int sidx[128];
  __shared__ int tidx[128];
  const int tid = (int)threadIdx.x;
  const int e0 = (int)blockIdx.x * 128;
  const int is64 = *flag_p;

  if (tid < 128) {
    const size_t e = (size_t)(e0 + tid);
    int s = 0, t = 0;
    if (e < (size_t)NE) {
      if (is64) {
        s = (int)eraw[2 * e];
        t = (int)eraw[2 * ((size_t)NE + e)];
      } else {
        s = (int)eraw[e];
        t = (int)eraw[(size_t)NE + e];
      }
    }
    sidx[tid] = s;
    tidx[tid] = t;
  }
  __syncthreads();

  // gather + add + relu -> Rs (f16, swizzled)
  {
    const int l16 = tid & 15;   // 16B chunk within row
    const int g = tid >> 4;     // 16 row-groups
#pragma unroll
    for (int i = 0; i < 8; ++i) {
      const int m = i * 16 + g;
      const half8_t av = *reinterpret_cast<const half8_t*>(
          At + (size_t)sidx[m] * DD + l16 * 8);
      const half8_t bv = *reinterpret_cast<const half8_t*>(
          Bt + (size_t)tidx[m] * DD + l16 * 8);
      half8_t r;
#pragma unroll
      for (int j = 0; j < 8; ++j) {
        const _Float16 s = av[j] + bv[j];
        r[j] = s > (_Float16)0 ? s : (_Float16)0;
      }
      *reinterpret_cast<half8_t*>(&Rs[swz16(m, l16 * 16) >> 1]) = r;
    }
  }
  __syncthreads();

  const int l = tid & 63;
  const int w = tid >> 6;
  const int lr = l & 15;
  const int lg = l >> 4;
  const int wrow = w * 32;

  f32x4 acc[2][8];
#pragma unroll
  for (int mf = 0; mf < 2; ++mf)
#pragma unroll
    for (int nf = 0; nf < 8; ++nf) acc[mf][nf] = (f32x4)0.f;

#pragma unroll
  for (int ks = 0; ks < 4; ++ks) {
    const half8_t a0 = *reinterpret_cast<const half8_t*>(
        &Rs[swz16(wrow + lr, lg * 16 + ks * 64) >> 1]);
    const half8_t a1 = *reinterpret_cast<const half8_t*>(
        &Rs[swz16(wrow + 16 + lr, lg * 16 + ks * 64) >> 1]);
#pragma unroll
    for (int nf = 0; nf < 8; ++nf) {
      const half8_t b = *reinterpret_cast<const half8_t*>(
          Wmlp_pk + ((size_t)(nf * 4 + ks) * 64 + l) * 8);
      acc[0][nf] = __builtin_amdgcn_mfma_f32_16x16x32_f16(a0, b, acc[0][nf], 0, 0, 0);
      acc[1][nf] = __builtin_amdgcn_mfma_f32_16x16x32_f16(a1, b, acc[1][nf], 0, 0, 0);
    }
  }

#pragma unroll
  for (int nf = 0; nf < 8; ++nf) {
    const int col = nf * 16 + lr;
    const float bm = bmlp[col];
#pragma unroll
    for (int mf = 0; mf < 2; ++mf) {
#pragma unroll
      for (int reg = 0; reg < 4; ++reg) {
        const int r = wrow + mf * 16 + lg * 4 + reg;
        const int e = e0 + r;
        if (e < NE)
          __builtin_nontemporal_store(acc[mf][nf][reg] + bm,
                                      out + (size_t)e * DD + col);
      }
    }
  }
}

// ---------------------------------------------------------------------------
extern "C" void kernel_launch(void* const* d_in, const int* in_sizes, int n_in,
                              void* d_out, int out_size, void* d_ws,
                              size_t ws_size, hipStream_t stream) {
  (void)in_sizes; (void)n_in; (void)out_size; (void)ws_size;

  const float* X = (const float*)d_in[0];
  const unsigned int* eraw = (const unsigned int*)d_in[1];
  const float* Wsrc = (const float*)d_in[2];
  const float* Wtgt = (const float*)d_in[3];
  const float* Wproj = (const float*)d_in[4];
  const float* bproj = (const float*)d_in[5];
  const float* Wmlp = (const float*)d_in[6];
  const float* bmlp = (const float*)d_in[7];
  float* out = (float*)d_out;

  // ws layout: A16[N*128] f16 | B16[N*128] f16 | packW[5*16384] f16 | flag
  _Float16* A16 = (_Float16*)d_ws;
  _Float16* B16 = A16 + (size_t)NN * DD;
  _Float16* packW = B16 + (size_t)NN * DD;
  int* flag = (int*)(packW + 5 * 16384);

  detect_idx64_kernel<<<1, 64, 0, stream>>>(eraw, flag);
  pack_weights_kernel<<<40, 256, 0, stream>>>(Wsrc, Wtgt, Wproj, Wmlp, packW);
  phase1_kernel<<<(NN + 63) / 64, 256, 0, stream>>>(X, packW, bproj, A16, B16);
  phase2_kernel<<<(NE + 127) / 128, 256, 0, stream>>>(A16, B16, eraw, flag,
                                                      packW + 4 * 16384, bmlp,
                                                      out);
}